// Round 9
// baseline (417.669 us; speedup 1.0000x reference)
//
#include <hip/hip_runtime.h>

#define NN 100000
#define NE 1600000

#define BSHIFT 9
#define NBKT 256            // compile-time max; used = (N+511)>>9 = 196
#define BCAP 12288          // per-bucket staging capacity (avg 8192, sd ~90)
#define TILE 16384

using half8 = __attribute__((ext_vector_type(8))) _Float16;
using f32x4 = __attribute__((ext_vector_type(4))) float;

// ---- bf16 helpers (round-to-nearest-even, matches numpy/jax cast) ----
__device__ inline unsigned short f2bf(float f) {
    unsigned int u = __float_as_uint(f);
    unsigned int r = (u + 0x7fffu + ((u >> 16) & 1u)) >> 16;
    return (unsigned short)r;
}
__device__ inline float bf2f(unsigned short h) {
    return __uint_as_float(((unsigned int)h) << 16);
}
__device__ inline float bflo(unsigned int v) { return __uint_as_float(v << 16); }
__device__ inline float bfhi(unsigned int v) { return __uint_as_float(v & 0xffff0000u); }
__device__ inline unsigned short f2h(float f) {
    union { _Float16 h; unsigned short u; } c; c.h = (_Float16)f; return c.u;
}

// ---------------- CSR build ----------------

__global__ void k_deg_count(const int* __restrict__ dst, int* __restrict__ cnt, int E) {
    int e = blockIdx.x * blockDim.x + threadIdx.x;
    if (e < E) atomicAdd(&cnt[dst[e]], 1);
}

__global__ void k_dinv(const int* __restrict__ cnt, float* __restrict__ dinv, int N) {
    int i = blockIdx.x * blockDim.x + threadIdx.x;
    if (i < N) dinv[i] = rsqrtf((float)(cnt[i] + 1));  // +1 self loop
}

__global__ void k_scan1(const int* __restrict__ cnt, int* __restrict__ excl,
                        int* __restrict__ bsums, int N) {
    __shared__ int s[512];
    int tid = threadIdx.x;
    int i = blockIdx.x * 512 + tid;
    int v = (i < N) ? cnt[i] : 0;
    s[tid] = v;
    __syncthreads();
    for (int off = 1; off < 512; off <<= 1) {
        int t = (tid >= off) ? s[tid - off] : 0;
        __syncthreads();
        s[tid] += t;
        __syncthreads();
    }
    if (i < N) excl[i] = s[tid] - v;
    if (tid == 511) bsums[blockIdx.x] = s[511];
}

__global__ void k_scan2(int* __restrict__ bsums, int nb) {
    if (blockIdx.x == 0 && threadIdx.x == 0) {
        int run = 0;
        for (int b = 0; b < nb; ++b) { int t = bsums[b]; bsums[b] = run; run += t; }
    }
}

__global__ void k_scan3(int* __restrict__ row_ptr, int* __restrict__ fill_ptr,
                        const int* __restrict__ bsums, int N, int E) {
    int i = blockIdx.x * blockDim.x + threadIdx.x;
    if (i < N) {
        int v = row_ptr[i] + bsums[i >> 9];
        row_ptr[i] = v;
        fill_ptr[i] = v;
    }
    if (i == 0) row_ptr[N] = E;
}

// ---- fill pass 1: bucketize edges by dst>>9 into per-bucket staging ----
// LDS histogram -> prefix -> LDS scatter -> coalesced burst copy-out.
__global__ __launch_bounds__(256) void k_bucket(
    const int* __restrict__ src, const int* __restrict__ dst,
    int* __restrict__ gcnt, unsigned* __restrict__ stage, int E) {
    __shared__ unsigned st[TILE];
    __shared__ int s[NBKT];          // scan workspace (inclusive)
    __shared__ int hist[NBKT];
    __shared__ int offs[NBKT + 1];
    __shared__ int cursor[NBKT];
    __shared__ int gbase[NBKT];
    int tid = threadIdx.x;
    int t0 = blockIdx.x * TILE;
    int m = E - t0; if (m > TILE) m = TILE;

    hist[tid] = 0;
    __syncthreads();
    for (int i = tid; i < m; i += 256)
        atomicAdd(&hist[dst[t0 + i] >> BSHIFT], 1);
    __syncthreads();
    // inclusive scan of hist (256 entries, 256 threads)
    s[tid] = hist[tid];
    __syncthreads();
    for (int off = 1; off < NBKT; off <<= 1) {
        int t = (tid >= off) ? s[tid - off] : 0;
        __syncthreads();
        s[tid] += t;
        __syncthreads();
    }
    offs[tid] = s[tid] - hist[tid];
    if (tid == 0) offs[NBKT] = m;
    cursor[tid] = s[tid] - hist[tid];
    gbase[tid] = atomicAdd(&gcnt[tid], hist[tid]);
    __syncthreads();
    // LDS scatter (packed: src<<9 | dst&511)
    for (int i = tid; i < m; i += 256) {
        int d = dst[t0 + i];
        int b = d >> BSHIFT;
        unsigned packed = ((unsigned)src[t0 + i] << BSHIFT) | (unsigned)(d & 511);
        int pos = atomicAdd(&cursor[b], 1);
        st[pos] = packed;
    }
    __syncthreads();
    // copy-out: element i belongs to bucket b with offs[b] <= i < offs[b+1]
    for (int i = tid; i < m; i += 256) {
        int lo = 0, hi = NBKT;
        while (hi - lo > 1) { int mid = (lo + hi) >> 1; if (offs[mid] <= i) lo = mid; else hi = mid; }
        int idx = gbase[lo] + (i - offs[lo]);
        if (idx < BCAP) stage[(size_t)lo * BCAP + idx] = st[i];
    }
}

// ---- fill pass 2: one block per bucket; col writes confined to ~32 KB region ----
__global__ void k_scatter(const unsigned* __restrict__ stage, const int* __restrict__ gcnt,
                          int* __restrict__ fill_ptr, int* __restrict__ col) {
    int b = blockIdx.x;
    int n = gcnt[b]; if (n > BCAP) n = BCAP;
    const unsigned* sg = stage + (size_t)b * BCAP;
    for (int i = threadIdx.x; i < n; i += blockDim.x) {
        unsigned e = sg[i];
        int d = (b << BSHIFT) | (int)(e & 511);
        int pos = atomicAdd(&fill_ptr[d], 1);
        col[pos] = (int)(e >> BSHIFT);
    }
}

// ---------------- f32 -> bf16 conversion (8 elems/thread) ----------------

__global__ void k_tobf16(const float* __restrict__ in, unsigned short* __restrict__ out, int n8) {
    int i = blockIdx.x * blockDim.x + threadIdx.x;
    if (i >= n8) return;
    const float4* p = (const float4*)(in + (size_t)i * 8);
    float4 a = p[0], b = p[1];
    uint4 o;
    o.x = (unsigned)f2bf(a.x) | ((unsigned)f2bf(a.y) << 16);
    o.y = (unsigned)f2bf(a.z) | ((unsigned)f2bf(a.w) << 16);
    o.z = (unsigned)f2bf(b.x) | ((unsigned)f2bf(b.y) << 16);
    o.w = (unsigned)f2bf(b.z) | ((unsigned)f2bf(b.w) << 16);
    ((uint4*)out)[i] = o;
}

// ---- pack W[K,128] f32 into f16 fragment-major layout for mfma_16x16x32 ----
__global__ void k_packW(const float* __restrict__ W, half8* __restrict__ wpack, int K) {
    int t = blockIdx.x * blockDim.x + threadIdx.x;
    int total = (K / 32) * 8 * 64;
    if (t >= total) return;
    int s = t >> 9;
    int j = (t >> 6) & 7;
    int l = t & 63;
    half8 hv;
#pragma unroll
    for (int jj = 0; jj < 8; ++jj)
        hv[jj] = (_Float16)W[(size_t)(32 * s + 8 * (l >> 4) + jj) * 128 + 16 * j + (l & 15)];
    wpack[t] = hv;
}

// ------- aggregation: wave/node; coalesced col staging, dinv gathered (L2-hit),
// ------- dinv[node] factored out; 8 row-gathers in flight; f16 output -------

template <int C>
__global__ void k_agg(const unsigned short* __restrict__ xb, const int* __restrict__ row_ptr,
                      const int* __restrict__ col, const float* __restrict__ dinv,
                      unsigned short* __restrict__ out, int N) {
    int node = blockIdx.x * (blockDim.x >> 6) + (threadIdx.x >> 6);
    int lane = threadIdx.x & 63;
    if (node >= N) return;
    int beg = row_ptr[node], end = row_ptr[node + 1];
    float di = dinv[node];

    if constexpr (C == 64) {
        float acc = 0.f;
        for (int base = beg; base < end; base += 64) {
            int m = end - base; if (m > 64) m = 64;
            int sel = (lane < m) ? lane : (m - 1);
            int cl = col[base + sel];
            float wl = (lane < m) ? dinv[cl] : 0.f;
            for (int k = 0; k < m; k += 8) {
                int c0 = __shfl(cl, k),     c1 = __shfl(cl, k + 1);
                int c2 = __shfl(cl, k + 2), c3 = __shfl(cl, k + 3);
                int c4 = __shfl(cl, k + 4), c5 = __shfl(cl, k + 5);
                int c6 = __shfl(cl, k + 6), c7 = __shfl(cl, k + 7);
                float w0 = __shfl(wl, k),     w1 = __shfl(wl, k + 1);
                float w2 = __shfl(wl, k + 2), w3 = __shfl(wl, k + 3);
                float w4 = __shfl(wl, k + 4), w5 = __shfl(wl, k + 5);
                float w6 = __shfl(wl, k + 6), w7 = __shfl(wl, k + 7);
                unsigned short v0 = xb[(size_t)c0 * 64 + lane];
                unsigned short v1 = xb[(size_t)c1 * 64 + lane];
                unsigned short v2 = xb[(size_t)c2 * 64 + lane];
                unsigned short v3 = xb[(size_t)c3 * 64 + lane];
                unsigned short v4 = xb[(size_t)c4 * 64 + lane];
                unsigned short v5 = xb[(size_t)c5 * 64 + lane];
                unsigned short v6 = xb[(size_t)c6 * 64 + lane];
                unsigned short v7 = xb[(size_t)c7 * 64 + lane];
                acc += w0 * bf2f(v0) + w1 * bf2f(v1) + w2 * bf2f(v2) + w3 * bf2f(v3)
                     + w4 * bf2f(v4) + w5 * bf2f(v5) + w6 * bf2f(v6) + w7 * bf2f(v7);
            }
        }
        acc = di * acc + di * di * bf2f(xb[(size_t)node * 64 + lane]);
        out[(size_t)node * 64 + lane] = f2h(acc);
    } else {
        const unsigned int* xb2 = (const unsigned int*)xb;  // 2 bf16 per uint
        float ax = 0.f, ay = 0.f;
        for (int base = beg; base < end; base += 64) {
            int m = end - base; if (m > 64) m = 64;
            int sel = (lane < m) ? lane : (m - 1);
            int cl = col[base + sel];
            float wl = (lane < m) ? dinv[cl] : 0.f;
            for (int k = 0; k < m; k += 8) {
                int c0 = __shfl(cl, k),     c1 = __shfl(cl, k + 1);
                int c2 = __shfl(cl, k + 2), c3 = __shfl(cl, k + 3);
                int c4 = __shfl(cl, k + 4), c5 = __shfl(cl, k + 5);
                int c6 = __shfl(cl, k + 6), c7 = __shfl(cl, k + 7);
                float w0 = __shfl(wl, k),     w1 = __shfl(wl, k + 1);
                float w2 = __shfl(wl, k + 2), w3 = __shfl(wl, k + 3);
                float w4 = __shfl(wl, k + 4), w5 = __shfl(wl, k + 5);
                float w6 = __shfl(wl, k + 6), w7 = __shfl(wl, k + 7);
                unsigned int v0 = xb2[(size_t)c0 * 64 + lane];
                unsigned int v1 = xb2[(size_t)c1 * 64 + lane];
                unsigned int v2 = xb2[(size_t)c2 * 64 + lane];
                unsigned int v3 = xb2[(size_t)c3 * 64 + lane];
                unsigned int v4 = xb2[(size_t)c4 * 64 + lane];
                unsigned int v5 = xb2[(size_t)c5 * 64 + lane];
                unsigned int v6 = xb2[(size_t)c6 * 64 + lane];
                unsigned int v7 = xb2[(size_t)c7 * 64 + lane];
                ax += w0 * bflo(v0) + w1 * bflo(v1) + w2 * bflo(v2) + w3 * bflo(v3)
                    + w4 * bflo(v4) + w5 * bflo(v5) + w6 * bflo(v6) + w7 * bflo(v7);
                ay += w0 * bfhi(v0) + w1 * bfhi(v1) + w2 * bfhi(v2) + w3 * bfhi(v3)
                    + w4 * bfhi(v4) + w5 * bfhi(v5) + w6 * bfhi(v6) + w7 * bfhi(v7);
            }
        }
        unsigned int v = xb2[(size_t)node * 64 + lane];
        ax = di * ax + di * di * bflo(v);
        ay = di * ay + di * di * bfhi(v);
        ((unsigned int*)out)[(size_t)node * 64 + lane] =
            (unsigned int)f2h(ax) | ((unsigned int)f2h(ay) << 16);
    }
}

// ------- MFMA GEMM (+bias+relu): out[N,128] = A[N,K](f16) @ W[K,128](f16) -------

template <int K, bool OUTBF>
__global__ __launch_bounds__(256) void k_gemm_mfma(
    const unsigned short* __restrict__ A, const half8* __restrict__ wpack,
    const float* __restrict__ bias, void* __restrict__ outp, int N) {
    int lane = threadIdx.x & 63;
    int wave = threadIdx.x >> 6;
    int row0 = blockIdx.x * 64 + wave * 16;
    int ar = row0 + (lane & 15);
    if (ar >= N) ar = N - 1;
    const _Float16* Ah = (const _Float16*)A;

    f32x4 acc[8];
#pragma unroll
    for (int j = 0; j < 8; ++j) acc[j] = (f32x4)(0.f);

#pragma unroll
    for (int s = 0; s < K / 32; ++s) {
        half8 av = *(const half8*)(Ah + (size_t)ar * K + 32 * s + 8 * (lane >> 4));
#pragma unroll
        for (int j = 0; j < 8; ++j) {
            half8 bv = wpack[(s * 8 + j) * 64 + lane];
            acc[j] = __builtin_amdgcn_mfma_f32_16x16x32_f16(av, bv, acc[j], 0, 0, 0);
        }
    }

    int rowb = row0 + (lane >> 4) * 4;
#pragma unroll
    for (int j = 0; j < 8; ++j) {
        int colc = j * 16 + (lane & 15);
        float b = bias[colc];
#pragma unroll
        for (int r = 0; r < 4; ++r) {
            int rr = rowb + r;
            if (rr < N) {
                float v = fmaxf(acc[j][r] + b, 0.f);
                if constexpr (OUTBF)
                    ((unsigned short*)outp)[(size_t)rr * 128 + colc] = f2bf(v);
                else
                    ((float*)outp)[(size_t)rr * 128 + colc] = v;
            }
        }
    }
}

// ---------------- pooling ----------------

__global__ void k_cntg_bs(const int* __restrict__ batch, int* __restrict__ cntg, int N) {
    int g = threadIdx.x;
    if (g >= 64) return;
    int lo = 0, hi = N;
    while (lo < hi) { int mid = (lo + hi) >> 1; if (batch[mid] < g) lo = mid + 1; else hi = mid; }
    int start = lo;
    lo = 0; hi = N;
    while (lo < hi) { int mid = (lo + hi) >> 1; if (batch[mid] < g + 1) lo = mid + 1; else hi = mid; }
    cntg[g] = lo - start;
}

#define POOL_NPB 64
__global__ void k_pool(const float* __restrict__ h, const int* __restrict__ batch,
                       float* __restrict__ pooled, int N) {
    int tid = threadIdx.x;  // 128 threads = channel
    int start = blockIdx.x * POOL_NPB;
    int end = start + POOL_NPB;
    if (end > N) end = N;
    if (start >= end) return;
    int curg = batch[start];
    float acc = 0.f;
    for (int n = start; n < end; ++n) {
        int g = batch[n];
        if (g != curg) {
            atomicAdd(&pooled[curg * 128 + tid], acc);
            acc = 0.f;
            curg = g;
        }
        acc += h[(size_t)n * 128 + tid];
    }
    atomicAdd(&pooled[curg * 128 + tid], acc);
}

__global__ void k_final(const float* __restrict__ pooled, const int* __restrict__ cntg,
                        const float* __restrict__ Wc, const float* __restrict__ bc,
                        float* __restrict__ out) {
    for (int idx = threadIdx.x; idx < 64 * 10; idx += 256) {
        int g = idx / 10, c = idx % 10;
        float s = 0.f;
        for (int k = 0; k < 128; ++k) s += pooled[g * 128 + k] * Wc[k * 10 + c];
        float cnt = (float)cntg[g];
        if (cnt < 1.f) cnt = 1.f;
        out[idx] = s / cnt + bc[c];
    }
}

// ---------------- launch ----------------

extern "C" void kernel_launch(void* const* d_in, const int* in_sizes, int n_in,
                              void* d_out, int out_size, void* d_ws, size_t ws_size,
                              hipStream_t stream) {
    const float* x  = (const float*)d_in[0];
    const float* W1 = (const float*)d_in[1];
    const float* b1 = (const float*)d_in[2];
    const float* W2 = (const float*)d_in[3];
    const float* b2 = (const float*)d_in[4];
    const float* Wc = (const float*)d_in[5];
    const float* bc = (const float*)d_in[6];
    const int* ei   = (const int*)d_in[7];
    const int* batch = (const int*)d_in[8];

    const int E = in_sizes[7] / 2;
    const int N = in_sizes[8];
    const int* src = ei;
    const int* dst = ei + E;

    char* p = (char*)d_ws;
    auto alloc = [&](size_t bytes) -> void* {
        void* r = (void*)p;
        p += (bytes + 255) & ~(size_t)255;
        return r;
    };
    int*   cnt      = (int*)alloc((size_t)N * 4);
    float* dinv     = (float*)alloc((size_t)N * 4);
    int*   row_ptr  = (int*)alloc((size_t)(N + 1) * 4);
    int*   fill_ptr = (int*)alloc((size_t)N * 4);
    int*   bsums    = (int*)alloc(4096);
    int*   col      = (int*)alloc((size_t)E * 4);
    int*   gcnt     = (int*)alloc(NBKT * 4);
    unsigned* stage = (unsigned*)alloc((size_t)NBKT * BCAP * 4);
    unsigned short* xb    = (unsigned short*)alloc((size_t)N * 64 * 2);
    unsigned short* h1b   = (unsigned short*)alloc((size_t)N * 128 * 2);
    unsigned short* aggb1 = (unsigned short*)alloc((size_t)N * 64 * 2);
    unsigned short* aggb2 = (unsigned short*)alloc((size_t)N * 128 * 2);
    half8* w1p      = (half8*)alloc(1024 * 16);
    half8* w2p      = (half8*)alloc(2048 * 16);
    float* bufB     = (float*)alloc((size_t)N * 128 * 4);
    float* pooled   = (float*)alloc(64 * 128 * 4);
    int*   cntg     = (int*)alloc(64 * 4);

    hipMemsetAsync(cnt, 0, (size_t)N * 4, stream);
    hipMemsetAsync(gcnt, 0, NBKT * 4, stream);
    hipMemsetAsync(pooled, 0, 64 * 128 * 4, stream);

    int nb = (N + 511) / 512;

    k_deg_count<<<(E + 255) / 256, 256, 0, stream>>>(dst, cnt, E);
    k_dinv<<<(N + 255) / 256, 256, 0, stream>>>(cnt, dinv, N);
    k_scan1<<<nb, 512, 0, stream>>>(cnt, row_ptr, bsums, N);
    k_scan2<<<1, 64, 0, stream>>>(bsums, nb);
    k_scan3<<<(N + 255) / 256, 256, 0, stream>>>(row_ptr, fill_ptr, bsums, N, E);

    // CSR fill: bucket sort (pass 1) + L2-local scatter (pass 2)
    k_bucket<<<(E + TILE - 1) / TILE, 256, 0, stream>>>(src, dst, gcnt, stage, E);
    k_scatter<<<nb, 256, 0, stream>>>(stage, gcnt, fill_ptr, col);

    // weight packs + x -> bf16
    k_packW<<<4, 256, 0, stream>>>(W1, w1p, 64);
    k_packW<<<8, 256, 0, stream>>>(W2, w2p, 128);
    k_tobf16<<<(N * 64 / 8 + 255) / 256, 256, 0, stream>>>(x, xb, N * 64 / 8);

    // layer 1: aggregate x_bf16 (64 ch) -> f16, MFMA transform -> h1 bf16
    k_agg<64><<<(N + 3) / 4, 256, 0, stream>>>(xb, row_ptr, col, dinv, aggb1, N);
    k_gemm_mfma<64, true><<<(N + 63) / 64, 256, 0, stream>>>(aggb1, w1p, b1, h1b, N);

    // layer 2: aggregate h1_bf16 (128 ch) -> f16, MFMA transform -> f32
    k_agg<128><<<(N + 3) / 4, 256, 0, stream>>>(h1b, row_ptr, col, dinv, aggb2, N);
    k_gemm_mfma<128, false><<<(N + 63) / 64, 256, 0, stream>>>(aggb2, w2p, b2, bufB, N);

    // pool + classify
    k_cntg_bs<<<1, 64, 0, stream>>>(batch, cntg, N);
    k_pool<<<(N + POOL_NPB - 1) / POOL_NPB, 128, 0, stream>>>(bufB, batch, pooled, N);
    k_final<<<1, 256, 0, stream>>>(pooled, cntg, Wc, bc, (float*)d_out);
}

// Round 10
// 364.427 us; speedup vs baseline: 1.1461x; 1.1461x over previous
//
#include <hip/hip_runtime.h>

#define NN 100000
#define NE 1600000

#define BSHIFT 9
#define NBKT 256            // compile-time max; used = (N+511)>>9 = 196
#define BCAP 12288          // per-bucket staging capacity (avg 8192, sd ~90)
#define TILE 4096

using half8 = __attribute__((ext_vector_type(8))) _Float16;
using f32x4 = __attribute__((ext_vector_type(4))) float;

// ---- bf16 helpers (round-to-nearest-even, matches numpy/jax cast) ----
__device__ inline unsigned short f2bf(float f) {
    unsigned int u = __float_as_uint(f);
    unsigned int r = (u + 0x7fffu + ((u >> 16) & 1u)) >> 16;
    return (unsigned short)r;
}
__device__ inline float bf2f(unsigned short h) {
    return __uint_as_float(((unsigned int)h) << 16);
}
__device__ inline float bflo(unsigned int v) { return __uint_as_float(v << 16); }
__device__ inline float bfhi(unsigned int v) { return __uint_as_float(v & 0xffff0000u); }
__device__ inline unsigned short f2h(float f) {
    union { _Float16 h; unsigned short u; } c; c.h = (_Float16)f; return c.u;
}

// ---------------- CSR build ----------------

__global__ void k_deg_count(const int* __restrict__ dst, int* __restrict__ cnt, int E) {
    int e = blockIdx.x * blockDim.x + threadIdx.x;
    if (e < E) atomicAdd(&cnt[dst[e]], 1);
}

__global__ void k_dinv(const int* __restrict__ cnt, float* __restrict__ dinv, int N) {
    int i = blockIdx.x * blockDim.x + threadIdx.x;
    if (i < N) dinv[i] = rsqrtf((float)(cnt[i] + 1));  // +1 self loop
}

__global__ void k_scan1(const int* __restrict__ cnt, int* __restrict__ excl,
                        int* __restrict__ bsums, int N) {
    __shared__ int s[512];
    int tid = threadIdx.x;
    int i = blockIdx.x * 512 + tid;
    int v = (i < N) ? cnt[i] : 0;
    s[tid] = v;
    __syncthreads();
    for (int off = 1; off < 512; off <<= 1) {
        int t = (tid >= off) ? s[tid - off] : 0;
        __syncthreads();
        s[tid] += t;
        __syncthreads();
    }
    if (i < N) excl[i] = s[tid] - v;
    if (tid == 511) bsums[blockIdx.x] = s[511];
}

__global__ void k_scan2(int* __restrict__ bsums, int nb) {
    if (blockIdx.x == 0 && threadIdx.x == 0) {
        int run = 0;
        for (int b = 0; b < nb; ++b) { int t = bsums[b]; bsums[b] = run; run += t; }
    }
}

__global__ void k_scan3(int* __restrict__ row_ptr, int* __restrict__ fill_ptr,
                        const int* __restrict__ bsums, int N, int E) {
    int i = blockIdx.x * blockDim.x + threadIdx.x;
    if (i < N) {
        int v = row_ptr[i] + bsums[i >> 9];
        row_ptr[i] = v;
        fill_ptr[i] = v;
    }
    if (i == 0) row_ptr[N] = E;
}

// ---- fill pass 1: bucketize edges by dst>>9 into per-bucket staging ----
// Wave-private LDS histograms -> prefix -> LDS scatter (bucket recorded) ->
// coalesced burst copy-out. TILE=4096 -> 391 blocks (parallelism).
__global__ __launch_bounds__(256) void k_bucket(
    const int* __restrict__ src, const int* __restrict__ dst,
    int* __restrict__ gcnt, unsigned* __restrict__ stage, int E) {
    __shared__ unsigned st[TILE];
    __shared__ unsigned char stb[TILE];
    __shared__ int hist4[4 * NBKT];
    __shared__ int hist[NBKT];
    __shared__ int s[NBKT];
    __shared__ int offs[NBKT];
    __shared__ int cursor[NBKT];
    __shared__ int gbase[NBKT];
    int tid = threadIdx.x;
    int wv = tid >> 6;
    int t0 = blockIdx.x * TILE;
    int m = E - t0; if (m > TILE) m = TILE;

    for (int i = tid; i < 4 * NBKT; i += 256) hist4[i] = 0;
    __syncthreads();
    for (int i = tid; i < m; i += 256)
        atomicAdd(&hist4[wv * NBKT + (dst[t0 + i] >> BSHIFT)], 1);
    __syncthreads();
    int h = hist4[tid] + hist4[NBKT + tid] + hist4[2 * NBKT + tid] + hist4[3 * NBKT + tid];
    hist[tid] = h;
    s[tid] = h;
    __syncthreads();
    for (int off = 1; off < NBKT; off <<= 1) {
        int t = (tid >= off) ? s[tid - off] : 0;
        __syncthreads();
        s[tid] += t;
        __syncthreads();
    }
    offs[tid] = s[tid] - hist[tid];
    cursor[tid] = s[tid] - hist[tid];
    gbase[tid] = atomicAdd(&gcnt[tid], hist[tid]);
    __syncthreads();
    // LDS scatter (packed: src<<9 | dst&511), record bucket per slot
    for (int i = tid; i < m; i += 256) {
        int d = dst[t0 + i];
        int b = d >> BSHIFT;
        unsigned packed = ((unsigned)src[t0 + i] << BSHIFT) | (unsigned)(d & 511);
        int pos = atomicAdd(&cursor[b], 1);
        st[pos] = packed;
        stb[pos] = (unsigned char)b;
    }
    __syncthreads();
    // copy-out: contiguous per-bucket bursts to global staging
    for (int i = tid; i < m; i += 256) {
        int b = stb[i];
        int idx = gbase[b] + (i - offs[b]);
        if (idx < BCAP) stage[(size_t)b * BCAP + idx] = st[i];
    }
}

// ---- fill pass 2: one block per bucket; col writes confined to ~32 KB region ----
__global__ void k_scatter(const unsigned* __restrict__ stage, const int* __restrict__ gcnt,
                          int* __restrict__ fill_ptr, int* __restrict__ col) {
    int b = blockIdx.x;
    int n = gcnt[b]; if (n > BCAP) n = BCAP;
    const unsigned* sg = stage + (size_t)b * BCAP;
    for (int i = threadIdx.x; i < n; i += blockDim.x) {
        unsigned e = sg[i];
        int d = (b << BSHIFT) | (int)(e & 511);
        int pos = atomicAdd(&fill_ptr[d], 1);
        col[pos] = (int)(e >> BSHIFT);
    }
}

// ---------------- f32 -> bf16 conversion (8 elems/thread) ----------------

__global__ void k_tobf16(const float* __restrict__ in, unsigned short* __restrict__ out, int n8) {
    int i = blockIdx.x * blockDim.x + threadIdx.x;
    if (i >= n8) return;
    const float4* p = (const float4*)(in + (size_t)i * 8);
    float4 a = p[0], b = p[1];
    uint4 o;
    o.x = (unsigned)f2bf(a.x) | ((unsigned)f2bf(a.y) << 16);
    o.y = (unsigned)f2bf(a.z) | ((unsigned)f2bf(a.w) << 16);
    o.z = (unsigned)f2bf(b.x) | ((unsigned)f2bf(b.y) << 16);
    o.w = (unsigned)f2bf(b.z) | ((unsigned)f2bf(b.w) << 16);
    ((uint4*)out)[i] = o;
}

// ---- pack W[K,128] f32 into f16 fragment-major layout for mfma_16x16x32 ----
__global__ void k_packW(const float* __restrict__ W, half8* __restrict__ wpack, int K) {
    int t = blockIdx.x * blockDim.x + threadIdx.x;
    int total = (K / 32) * 8 * 64;
    if (t >= total) return;
    int s = t >> 9;
    int j = (t >> 6) & 7;
    int l = t & 63;
    half8 hv;
#pragma unroll
    for (int jj = 0; jj < 8; ++jj)
        hv[jj] = (_Float16)W[(size_t)(32 * s + 8 * (l >> 4) + jj) * 128 + 16 * j + (l & 15)];
    wpack[t] = hv;
}

// ------- aggregation: wave/node; coalesced col staging, dinv gathered (L2-hit),
// ------- dinv[node] factored out; 8 row-gathers in flight; f16 output -------

template <int C>
__global__ void k_agg(const unsigned short* __restrict__ xb, const int* __restrict__ row_ptr,
                      const int* __restrict__ col, const float* __restrict__ dinv,
                      unsigned short* __restrict__ out, int N) {
    int node = blockIdx.x * (blockDim.x >> 6) + (threadIdx.x >> 6);
    int lane = threadIdx.x & 63;
    if (node >= N) return;
    int beg = row_ptr[node], end = row_ptr[node + 1];
    float di = dinv[node];

    if constexpr (C == 64) {
        float acc = 0.f;
        for (int base = beg; base < end; base += 64) {
            int m = end - base; if (m > 64) m = 64;
            int sel = (lane < m) ? lane : (m - 1);
            int cl = col[base + sel];
            float wl = (lane < m) ? dinv[cl] : 0.f;
            for (int k = 0; k < m; k += 8) {
                int c0 = __shfl(cl, k),     c1 = __shfl(cl, k + 1);
                int c2 = __shfl(cl, k + 2), c3 = __shfl(cl, k + 3);
                int c4 = __shfl(cl, k + 4), c5 = __shfl(cl, k + 5);
                int c6 = __shfl(cl, k + 6), c7 = __shfl(cl, k + 7);
                float w0 = __shfl(wl, k),     w1 = __shfl(wl, k + 1);
                float w2 = __shfl(wl, k + 2), w3 = __shfl(wl, k + 3);
                float w4 = __shfl(wl, k + 4), w5 = __shfl(wl, k + 5);
                float w6 = __shfl(wl, k + 6), w7 = __shfl(wl, k + 7);
                unsigned short v0 = xb[(size_t)c0 * 64 + lane];
                unsigned short v1 = xb[(size_t)c1 * 64 + lane];
                unsigned short v2 = xb[(size_t)c2 * 64 + lane];
                unsigned short v3 = xb[(size_t)c3 * 64 + lane];
                unsigned short v4 = xb[(size_t)c4 * 64 + lane];
                unsigned short v5 = xb[(size_t)c5 * 64 + lane];
                unsigned short v6 = xb[(size_t)c6 * 64 + lane];
                unsigned short v7 = xb[(size_t)c7 * 64 + lane];
                acc += w0 * bf2f(v0) + w1 * bf2f(v1) + w2 * bf2f(v2) + w3 * bf2f(v3)
                     + w4 * bf2f(v4) + w5 * bf2f(v5) + w6 * bf2f(v6) + w7 * bf2f(v7);
            }
        }
        acc = di * acc + di * di * bf2f(xb[(size_t)node * 64 + lane]);
        out[(size_t)node * 64 + lane] = f2h(acc);
    } else {
        const unsigned int* xb2 = (const unsigned int*)xb;  // 2 bf16 per uint
        float ax = 0.f, ay = 0.f;
        for (int base = beg; base < end; base += 64) {
            int m = end - base; if (m > 64) m = 64;
            int sel = (lane < m) ? lane : (m - 1);
            int cl = col[base + sel];
            float wl = (lane < m) ? dinv[cl] : 0.f;
            for (int k = 0; k < m; k += 8) {
                int c0 = __shfl(cl, k),     c1 = __shfl(cl, k + 1);
                int c2 = __shfl(cl, k + 2), c3 = __shfl(cl, k + 3);
                int c4 = __shfl(cl, k + 4), c5 = __shfl(cl, k + 5);
                int c6 = __shfl(cl, k + 6), c7 = __shfl(cl, k + 7);
                float w0 = __shfl(wl, k),     w1 = __shfl(wl, k + 1);
                float w2 = __shfl(wl, k + 2), w3 = __shfl(wl, k + 3);
                float w4 = __shfl(wl, k + 4), w5 = __shfl(wl, k + 5);
                float w6 = __shfl(wl, k + 6), w7 = __shfl(wl, k + 7);
                unsigned int v0 = xb2[(size_t)c0 * 64 + lane];
                unsigned int v1 = xb2[(size_t)c1 * 64 + lane];
                unsigned int v2 = xb2[(size_t)c2 * 64 + lane];
                unsigned int v3 = xb2[(size_t)c3 * 64 + lane];
                unsigned int v4 = xb2[(size_t)c4 * 64 + lane];
                unsigned int v5 = xb2[(size_t)c5 * 64 + lane];
                unsigned int v6 = xb2[(size_t)c6 * 64 + lane];
                unsigned int v7 = xb2[(size_t)c7 * 64 + lane];
                ax += w0 * bflo(v0) + w1 * bflo(v1) + w2 * bflo(v2) + w3 * bflo(v3)
                    + w4 * bflo(v4) + w5 * bflo(v5) + w6 * bflo(v6) + w7 * bflo(v7);
                ay += w0 * bfhi(v0) + w1 * bfhi(v1) + w2 * bfhi(v2) + w3 * bfhi(v3)
                    + w4 * bfhi(v4) + w5 * bfhi(v5) + w6 * bfhi(v6) + w7 * bfhi(v7);
            }
        }
        unsigned int v = xb2[(size_t)node * 64 + lane];
        ax = di * ax + di * di * bflo(v);
        ay = di * ay + di * di * bfhi(v);
        ((unsigned int*)out)[(size_t)node * 64 + lane] =
            (unsigned int)f2h(ax) | ((unsigned int)f2h(ay) << 16);
    }
}

// ------- MFMA GEMM (+bias+relu): out[N,128] = A[N,K](f16) @ W[K,128](f16) -------

template <int K, bool OUTBF>
__global__ __launch_bounds__(256) void k_gemm_mfma(
    const unsigned short* __restrict__ A, const half8* __restrict__ wpack,
    const float* __restrict__ bias, void* __restrict__ outp, int N) {
    int lane = threadIdx.x & 63;
    int wave = threadIdx.x >> 6;
    int row0 = blockIdx.x * 64 + wave * 16;
    int ar = row0 + (lane & 15);
    if (ar >= N) ar = N - 1;
    const _Float16* Ah = (const _Float16*)A;

    f32x4 acc[8];
#pragma unroll
    for (int j = 0; j < 8; ++j) acc[j] = (f32x4)(0.f);

#pragma unroll
    for (int s = 0; s < K / 32; ++s) {
        half8 av = *(const half8*)(Ah + (size_t)ar * K + 32 * s + 8 * (lane >> 4));
#pragma unroll
        for (int j = 0; j < 8; ++j) {
            half8 bv = wpack[(s * 8 + j) * 64 + lane];
            acc[j] = __builtin_amdgcn_mfma_f32_16x16x32_f16(av, bv, acc[j], 0, 0, 0);
        }
    }

    int rowb = row0 + (lane >> 4) * 4;
#pragma unroll
    for (int j = 0; j < 8; ++j) {
        int colc = j * 16 + (lane & 15);
        float b = bias[colc];
#pragma unroll
        for (int r = 0; r < 4; ++r) {
            int rr = rowb + r;
            if (rr < N) {
                float v = fmaxf(acc[j][r] + b, 0.f);
                if constexpr (OUTBF)
                    ((unsigned short*)outp)[(size_t)rr * 128 + colc] = f2bf(v);
                else
                    ((float*)outp)[(size_t)rr * 128 + colc] = v;
            }
        }
    }
}

// ---------------- pooling ----------------

__global__ void k_cntg_bs(const int* __restrict__ batch, int* __restrict__ cntg, int N) {
    int g = threadIdx.x;
    if (g >= 64) return;
    int lo = 0, hi = N;
    while (lo < hi) { int mid = (lo + hi) >> 1; if (batch[mid] < g) lo = mid + 1; else hi = mid; }
    int start = lo;
    lo = 0; hi = N;
    while (lo < hi) { int mid = (lo + hi) >> 1; if (batch[mid] < g + 1) lo = mid + 1; else hi = mid; }
    cntg[g] = lo - start;
}

#define POOL_NPB 64
__global__ void k_pool(const float* __restrict__ h, const int* __restrict__ batch,
                       float* __restrict__ pooled, int N) {
    int tid = threadIdx.x;  // 128 threads = channel
    int start = blockIdx.x * POOL_NPB;
    int end = start + POOL_NPB;
    if (end > N) end = N;
    if (start >= end) return;
    int curg = batch[start];
    float acc = 0.f;
    for (int n = start; n < end; ++n) {
        int g = batch[n];
        if (g != curg) {
            atomicAdd(&pooled[curg * 128 + tid], acc);
            acc = 0.f;
            curg = g;
        }
        acc += h[(size_t)n * 128 + tid];
    }
    atomicAdd(&pooled[curg * 128 + tid], acc);
}

__global__ void k_final(const float* __restrict__ pooled, const int* __restrict__ cntg,
                        const float* __restrict__ Wc, const float* __restrict__ bc,
                        float* __restrict__ out) {
    for (int idx = threadIdx.x; idx < 64 * 10; idx += 256) {
        int g = idx / 10, c = idx % 10;
        float s = 0.f;
        for (int k = 0; k < 128; ++k) s += pooled[g * 128 + k] * Wc[k * 10 + c];
        float cnt = (float)cntg[g];
        if (cnt < 1.f) cnt = 1.f;
        out[idx] = s / cnt + bc[c];
    }
}

// ---------------- launch ----------------

extern "C" void kernel_launch(void* const* d_in, const int* in_sizes, int n_in,
                              void* d_out, int out_size, void* d_ws, size_t ws_size,
                              hipStream_t stream) {
    const float* x  = (const float*)d_in[0];
    const float* W1 = (const float*)d_in[1];
    const float* b1 = (const float*)d_in[2];
    const float* W2 = (const float*)d_in[3];
    const float* b2 = (const float*)d_in[4];
    const float* Wc = (const float*)d_in[5];
    const float* bc = (const float*)d_in[6];
    const int* ei   = (const int*)d_in[7];
    const int* batch = (const int*)d_in[8];

    const int E = in_sizes[7] / 2;
    const int N = in_sizes[8];
    const int* src = ei;
    const int* dst = ei + E;

    char* p = (char*)d_ws;
    auto alloc = [&](size_t bytes) -> void* {
        void* r = (void*)p;
        p += (bytes + 255) & ~(size_t)255;
        return r;
    };
    int*   cnt      = (int*)alloc((size_t)N * 4);
    float* dinv     = (float*)alloc((size_t)N * 4);
    int*   row_ptr  = (int*)alloc((size_t)(N + 1) * 4);
    int*   fill_ptr = (int*)alloc((size_t)N * 4);
    int*   bsums    = (int*)alloc(4096);
    int*   col      = (int*)alloc((size_t)E * 4);
    int*   gcnt     = (int*)alloc(NBKT * 4);
    unsigned* stage = (unsigned*)alloc((size_t)NBKT * BCAP * 4);
    unsigned short* xb    = (unsigned short*)alloc((size_t)N * 64 * 2);
    unsigned short* h1b   = (unsigned short*)alloc((size_t)N * 128 * 2);
    unsigned short* aggb1 = (unsigned short*)alloc((size_t)N * 64 * 2);
    unsigned short* aggb2 = (unsigned short*)alloc((size_t)N * 128 * 2);
    half8* w1p      = (half8*)alloc(1024 * 16);
    half8* w2p      = (half8*)alloc(2048 * 16);
    float* bufB     = (float*)alloc((size_t)N * 128 * 4);
    float* pooled   = (float*)alloc(64 * 128 * 4);
    int*   cntg     = (int*)alloc(64 * 4);

    hipMemsetAsync(cnt, 0, (size_t)N * 4, stream);
    hipMemsetAsync(gcnt, 0, NBKT * 4, stream);
    hipMemsetAsync(pooled, 0, 64 * 128 * 4, stream);

    int nb = (N + 511) / 512;

    k_deg_count<<<(E + 255) / 256, 256, 0, stream>>>(dst, cnt, E);
    k_dinv<<<(N + 255) / 256, 256, 0, stream>>>(cnt, dinv, N);
    k_scan1<<<nb, 512, 0, stream>>>(cnt, row_ptr, bsums, N);
    k_scan2<<<1, 64, 0, stream>>>(bsums, nb);
    k_scan3<<<(N + 255) / 256, 256, 0, stream>>>(row_ptr, fill_ptr, bsums, N, E);

    // CSR fill: bucket sort (pass 1) + L2-local scatter (pass 2)
    k_bucket<<<(E + TILE - 1) / TILE, 256, 0, stream>>>(src, dst, gcnt, stage, E);
    k_scatter<<<nb, 256, 0, stream>>>(stage, gcnt, fill_ptr, col);

    // weight packs + x -> bf16
    k_packW<<<4, 256, 0, stream>>>(W1, w1p, 64);
    k_packW<<<8, 256, 0, stream>>>(W2, w2p, 128);
    k_tobf16<<<(N * 64 / 8 + 255) / 256, 256, 0, stream>>>(x, xb, N * 64 / 8);

    // layer 1: aggregate x_bf16 (64 ch) -> f16, MFMA transform -> h1 bf16
    k_agg<64><<<(N + 3) / 4, 256, 0, stream>>>(xb, row_ptr, col, dinv, aggb1, N);
    k_gemm_mfma<64, true><<<(N + 63) / 64, 256, 0, stream>>>(aggb1, w1p, b1, h1b, N);

    // layer 2: aggregate h1_bf16 (128 ch) -> f16, MFMA transform -> f32
    k_agg<128><<<(N + 3) / 4, 256, 0, stream>>>(h1b, row_ptr, col, dinv, aggb2, N);
    k_gemm_mfma<128, false><<<(N + 63) / 64, 256, 0, stream>>>(aggb2, w2p, b2, bufB, N);

    // pool + classify
    k_cntg_bs<<<1, 64, 0, stream>>>(batch, cntg, N);
    k_pool<<<(N + POOL_NPB - 1) / POOL_NPB, 128, 0, stream>>>(bufB, batch, pooled, N);
    k_final<<<1, 256, 0, stream>>>(pooled, cntg, Wc, bc, (float*)d_out);
}

// Round 11
// 277.532 us; speedup vs baseline: 1.5049x; 1.3131x over previous
//
#include <hip/hip_runtime.h>

#define NN 100000
#define NE 1600000

#define BSHIFT 9
#define NBKT 256            // compile-time max; used = (N+511)>>9 = 196
#define BCAP 12288          // per-bucket staging capacity (avg 8192, sd ~90)
#define TILE 4096

using half8 = __attribute__((ext_vector_type(8))) _Float16;
using f32x4 = __attribute__((ext_vector_type(4))) float;

// ---- bf16 helpers (round-to-nearest-even, matches numpy/jax cast) ----
__device__ inline unsigned short f2bf(float f) {
    unsigned int u = __float_as_uint(f);
    unsigned int r = (u + 0x7fffu + ((u >> 16) & 1u)) >> 16;
    return (unsigned short)r;
}
__device__ inline float bf2f(unsigned short h) {
    return __uint_as_float(((unsigned int)h) << 16);
}
__device__ inline float bflo(unsigned int v) { return __uint_as_float(v << 16); }
__device__ inline float bfhi(unsigned int v) { return __uint_as_float(v & 0xffff0000u); }
__device__ inline unsigned short f2h(float f) {
    union { _Float16 h; unsigned short u; } c; c.h = (_Float16)f; return c.u;
}

// ---- fill pass 1: bucketize edges by dst>>9 into per-bucket staging ----
__global__ __launch_bounds__(256) void k_bucket(
    const int* __restrict__ src, const int* __restrict__ dst,
    int* __restrict__ gcnt, unsigned* __restrict__ stage, int E) {
    __shared__ unsigned st[TILE];
    __shared__ unsigned char stb[TILE];
    __shared__ int hist4[4 * NBKT];
    __shared__ int hist[NBKT];
    __shared__ int s[NBKT];
    __shared__ int offs[NBKT];
    __shared__ int cursor[NBKT];
    __shared__ int gbase[NBKT];
    int tid = threadIdx.x;
    int wv = tid >> 6;
    int t0 = blockIdx.x * TILE;
    int m = E - t0; if (m > TILE) m = TILE;

    for (int i = tid; i < 4 * NBKT; i += 256) hist4[i] = 0;
    __syncthreads();
    for (int i = tid; i < m; i += 256)
        atomicAdd(&hist4[wv * NBKT + (dst[t0 + i] >> BSHIFT)], 1);
    __syncthreads();
    int h = hist4[tid] + hist4[NBKT + tid] + hist4[2 * NBKT + tid] + hist4[3 * NBKT + tid];
    hist[tid] = h;
    s[tid] = h;
    __syncthreads();
    for (int off = 1; off < NBKT; off <<= 1) {
        int t = (tid >= off) ? s[tid - off] : 0;
        __syncthreads();
        s[tid] += t;
        __syncthreads();
    }
    offs[tid] = s[tid] - hist[tid];
    cursor[tid] = s[tid] - hist[tid];
    gbase[tid] = atomicAdd(&gcnt[tid], hist[tid]);
    __syncthreads();
    for (int i = tid; i < m; i += 256) {
        int d = dst[t0 + i];
        int b = d >> BSHIFT;
        unsigned packed = ((unsigned)src[t0 + i] << BSHIFT) | (unsigned)(d & 511);
        int pos = atomicAdd(&cursor[b], 1);
        st[pos] = packed;
        stb[pos] = (unsigned char)b;
    }
    __syncthreads();
    for (int i = tid; i < m; i += 256) {
        int b = stb[i];
        int idx = gbase[b] + (i - offs[b]);
        if (idx < BCAP) stage[(size_t)b * BCAP + idx] = st[i];
    }
}

// ---- degree count from stage: LDS histogram per bucket, no global atomics ----
__global__ __launch_bounds__(512) void k_cnt_bucket(
    const unsigned* __restrict__ stage, const int* __restrict__ gcnt,
    int* __restrict__ cnt, int N) {
    __shared__ int h[512];
    int b = blockIdx.x;
    int tid = threadIdx.x;
    h[tid] = 0;
    __syncthreads();
    int n = gcnt[b]; if (n > BCAP) n = BCAP;
    const unsigned* sg = stage + (size_t)b * BCAP;
    for (int i = tid; i < n; i += 512)
        atomicAdd(&h[sg[i] & 511], 1);
    __syncthreads();
    int d = (b << BSHIFT) | tid;
    if (d < N) cnt[d] = h[tid];
}

__global__ void k_dinv(const int* __restrict__ cnt, float* __restrict__ dinv, int N) {
    int i = blockIdx.x * blockDim.x + threadIdx.x;
    if (i < N) dinv[i] = rsqrtf((float)(cnt[i] + 1));  // +1 self loop
}

__global__ void k_scan1(const int* __restrict__ cnt, int* __restrict__ excl,
                        int* __restrict__ bsums, int N) {
    __shared__ int s[512];
    int tid = threadIdx.x;
    int i = blockIdx.x * 512 + tid;
    int v = (i < N) ? cnt[i] : 0;
    s[tid] = v;
    __syncthreads();
    for (int off = 1; off < 512; off <<= 1) {
        int t = (tid >= off) ? s[tid - off] : 0;
        __syncthreads();
        s[tid] += t;
        __syncthreads();
    }
    if (i < N) excl[i] = s[tid] - v;
    if (tid == 511) bsums[blockIdx.x] = s[511];
}

__global__ void k_scan2(int* __restrict__ bsums, int nb) {
    if (blockIdx.x == 0 && threadIdx.x == 0) {
        int run = 0;
        for (int b = 0; b < nb; ++b) { int t = bsums[b]; bsums[b] = run; run += t; }
    }
}

__global__ void k_scan3(int* __restrict__ row_ptr, const int* __restrict__ bsums,
                        int N, int E) {
    int i = blockIdx.x * blockDim.x + threadIdx.x;
    if (i < N) row_ptr[i] += bsums[i >> 9];
    if (i == 0) row_ptr[N] = E;
}

// ---- fill pass 2: one block per bucket; LDS cursors (bucket-exclusive nodes) ----
__global__ __launch_bounds__(512) void k_scatter(
    const unsigned* __restrict__ stage, const int* __restrict__ gcnt,
    const int* __restrict__ row_ptr, int* __restrict__ col, int N) {
    __shared__ int cur[512];
    int b = blockIdx.x;
    int tid = threadIdx.x;
    int d0 = (b << BSHIFT) | tid;
    cur[tid] = (d0 < N) ? row_ptr[d0] : 0;
    __syncthreads();
    int n = gcnt[b]; if (n > BCAP) n = BCAP;
    const unsigned* sg = stage + (size_t)b * BCAP;
    for (int i = tid; i < n; i += 512) {
        unsigned e = sg[i];
        int pos = atomicAdd(&cur[e & 511], 1);
        col[pos] = (int)(e >> BSHIFT);
    }
}

// ---------------- f32 -> bf16 conversion (8 elems/thread) ----------------

__global__ void k_tobf16(const float* __restrict__ in, unsigned short* __restrict__ out, int n8) {
    int i = blockIdx.x * blockDim.x + threadIdx.x;
    if (i >= n8) return;
    const float4* p = (const float4*)(in + (size_t)i * 8);
    float4 a = p[0], b = p[1];
    uint4 o;
    o.x = (unsigned)f2bf(a.x) | ((unsigned)f2bf(a.y) << 16);
    o.y = (unsigned)f2bf(a.z) | ((unsigned)f2bf(a.w) << 16);
    o.z = (unsigned)f2bf(b.x) | ((unsigned)f2bf(b.y) << 16);
    o.w = (unsigned)f2bf(b.z) | ((unsigned)f2bf(b.w) << 16);
    ((uint4*)out)[i] = o;
}

// ---- pack W[K,128] f32 into f16 fragment-major layout for mfma_16x16x32 ----
__global__ void k_packW(const float* __restrict__ W, half8* __restrict__ wpack, int K) {
    int t = blockIdx.x * blockDim.x + threadIdx.x;
    int total = (K / 32) * 8 * 64;
    if (t >= total) return;
    int s = t >> 9;
    int j = (t >> 6) & 7;
    int l = t & 63;
    half8 hv;
#pragma unroll
    for (int jj = 0; jj < 8; ++jj)
        hv[jj] = (_Float16)W[(size_t)(32 * s + 8 * (l >> 4) + jj) * 128 + 16 * j + (l & 15)];
    wpack[t] = hv;
}

// ------- aggregation: wave/node; coalesced col staging, dinv gathered (L2-hit),
// ------- dinv[node] factored out; 8 row-gathers in flight; f16 output -------

template <int C>
__global__ void k_agg(const unsigned short* __restrict__ xb, const int* __restrict__ row_ptr,
                      const int* __restrict__ col, const float* __restrict__ dinv,
                      unsigned short* __restrict__ out, int N) {
    int node = blockIdx.x * (blockDim.x >> 6) + (threadIdx.x >> 6);
    int lane = threadIdx.x & 63;
    if (node >= N) return;
    int beg = row_ptr[node], end = row_ptr[node + 1];
    float di = dinv[node];

    if constexpr (C == 64) {
        float acc = 0.f;
        for (int base = beg; base < end; base += 64) {
            int m = end - base; if (m > 64) m = 64;
            int sel = (lane < m) ? lane : (m - 1);
            int cl = col[base + sel];
            float wl = (lane < m) ? dinv[cl] : 0.f;
            for (int k = 0; k < m; k += 8) {
                int c0 = __shfl(cl, k),     c1 = __shfl(cl, k + 1);
                int c2 = __shfl(cl, k + 2), c3 = __shfl(cl, k + 3);
                int c4 = __shfl(cl, k + 4), c5 = __shfl(cl, k + 5);
                int c6 = __shfl(cl, k + 6), c7 = __shfl(cl, k + 7);
                float w0 = __shfl(wl, k),     w1 = __shfl(wl, k + 1);
                float w2 = __shfl(wl, k + 2), w3 = __shfl(wl, k + 3);
                float w4 = __shfl(wl, k + 4), w5 = __shfl(wl, k + 5);
                float w6 = __shfl(wl, k + 6), w7 = __shfl(wl, k + 7);
                unsigned short v0 = xb[(size_t)c0 * 64 + lane];
                unsigned short v1 = xb[(size_t)c1 * 64 + lane];
                unsigned short v2 = xb[(size_t)c2 * 64 + lane];
                unsigned short v3 = xb[(size_t)c3 * 64 + lane];
                unsigned short v4 = xb[(size_t)c4 * 64 + lane];
                unsigned short v5 = xb[(size_t)c5 * 64 + lane];
                unsigned short v6 = xb[(size_t)c6 * 64 + lane];
                unsigned short v7 = xb[(size_t)c7 * 64 + lane];
                acc += w0 * bf2f(v0) + w1 * bf2f(v1) + w2 * bf2f(v2) + w3 * bf2f(v3)
                     + w4 * bf2f(v4) + w5 * bf2f(v5) + w6 * bf2f(v6) + w7 * bf2f(v7);
            }
        }
        acc = di * acc + di * di * bf2f(xb[(size_t)node * 64 + lane]);
        out[(size_t)node * 64 + lane] = f2h(acc);
    } else {
        const unsigned int* xb2 = (const unsigned int*)xb;  // 2 bf16 per uint
        float ax = 0.f, ay = 0.f;
        for (int base = beg; base < end; base += 64) {
            int m = end - base; if (m > 64) m = 64;
            int sel = (lane < m) ? lane : (m - 1);
            int cl = col[base + sel];
            float wl = (lane < m) ? dinv[cl] : 0.f;
            for (int k = 0; k < m; k += 8) {
                int c0 = __shfl(cl, k),     c1 = __shfl(cl, k + 1);
                int c2 = __shfl(cl, k + 2), c3 = __shfl(cl, k + 3);
                int c4 = __shfl(cl, k + 4), c5 = __shfl(cl, k + 5);
                int c6 = __shfl(cl, k + 6), c7 = __shfl(cl, k + 7);
                float w0 = __shfl(wl, k),     w1 = __shfl(wl, k + 1);
                float w2 = __shfl(wl, k + 2), w3 = __shfl(wl, k + 3);
                float w4 = __shfl(wl, k + 4), w5 = __shfl(wl, k + 5);
                float w6 = __shfl(wl, k + 6), w7 = __shfl(wl, k + 7);
                unsigned int v0 = xb2[(size_t)c0 * 64 + lane];
                unsigned int v1 = xb2[(size_t)c1 * 64 + lane];
                unsigned int v2 = xb2[(size_t)c2 * 64 + lane];
                unsigned int v3 = xb2[(size_t)c3 * 64 + lane];
                unsigned int v4 = xb2[(size_t)c4 * 64 + lane];
                unsigned int v5 = xb2[(size_t)c5 * 64 + lane];
                unsigned int v6 = xb2[(size_t)c6 * 64 + lane];
                unsigned int v7 = xb2[(size_t)c7 * 64 + lane];
                ax += w0 * bflo(v0) + w1 * bflo(v1) + w2 * bflo(v2) + w3 * bflo(v3)
                    + w4 * bflo(v4) + w5 * bflo(v5) + w6 * bflo(v6) + w7 * bflo(v7);
                ay += w0 * bfhi(v0) + w1 * bfhi(v1) + w2 * bfhi(v2) + w3 * bfhi(v3)
                    + w4 * bfhi(v4) + w5 * bfhi(v5) + w6 * bfhi(v6) + w7 * bfhi(v7);
            }
        }
        unsigned int v = xb2[(size_t)node * 64 + lane];
        ax = di * ax + di * di * bflo(v);
        ay = di * ay + di * di * bfhi(v);
        ((unsigned int*)out)[(size_t)node * 64 + lane] =
            (unsigned int)f2h(ax) | ((unsigned int)f2h(ay) << 16);
    }
}

// ------- MFMA GEMM (+bias+relu): out[N,128] = A[N,K](f16) @ W[K,128](f16) -------

template <int K, bool OUTBF>
__global__ __launch_bounds__(256) void k_gemm_mfma(
    const unsigned short* __restrict__ A, const half8* __restrict__ wpack,
    const float* __restrict__ bias, void* __restrict__ outp, int N) {
    int lane = threadIdx.x & 63;
    int wave = threadIdx.x >> 6;
    int row0 = blockIdx.x * 64 + wave * 16;
    int ar = row0 + (lane & 15);
    if (ar >= N) ar = N - 1;
    const _Float16* Ah = (const _Float16*)A;

    f32x4 acc[8];
#pragma unroll
    for (int j = 0; j < 8; ++j) acc[j] = (f32x4)(0.f);

#pragma unroll
    for (int s = 0; s < K / 32; ++s) {
        half8 av = *(const half8*)(Ah + (size_t)ar * K + 32 * s + 8 * (lane >> 4));
#pragma unroll
        for (int j = 0; j < 8; ++j) {
            half8 bv = wpack[(s * 8 + j) * 64 + lane];
            acc[j] = __builtin_amdgcn_mfma_f32_16x16x32_f16(av, bv, acc[j], 0, 0, 0);
        }
    }

    int rowb = row0 + (lane >> 4) * 4;
#pragma unroll
    for (int j = 0; j < 8; ++j) {
        int colc = j * 16 + (lane & 15);
        float b = bias[colc];
#pragma unroll
        for (int r = 0; r < 4; ++r) {
            int rr = rowb + r;
            if (rr < N) {
                float v = fmaxf(acc[j][r] + b, 0.f);
                if constexpr (OUTBF)
                    ((unsigned short*)outp)[(size_t)rr * 128 + colc] = f2bf(v);
                else
                    ((float*)outp)[(size_t)rr * 128 + colc] = v;
            }
        }
    }
}

// ---------------- pooling ----------------

__global__ void k_cntg_bs(const int* __restrict__ batch, int* __restrict__ cntg, int N) {
    int g = threadIdx.x;
    if (g >= 64) return;
    int lo = 0, hi = N;
    while (lo < hi) { int mid = (lo + hi) >> 1; if (batch[mid] < g) lo = mid + 1; else hi = mid; }
    int start = lo;
    lo = 0; hi = N;
    while (lo < hi) { int mid = (lo + hi) >> 1; if (batch[mid] < g + 1) lo = mid + 1; else hi = mid; }
    cntg[g] = lo - start;
}

#define POOL_NPB 64
__global__ void k_pool(const float* __restrict__ h, const int* __restrict__ batch,
                       float* __restrict__ pooled, int N) {
    int tid = threadIdx.x;  // 128 threads = channel
    int start = blockIdx.x * POOL_NPB;
    int end = start + POOL_NPB;
    if (end > N) end = N;
    if (start >= end) return;
    int curg = batch[start];
    float acc = 0.f;
    for (int n = start; n < end; ++n) {
        int g = batch[n];
        if (g != curg) {
            atomicAdd(&pooled[curg * 128 + tid], acc);
            acc = 0.f;
            curg = g;
        }
        acc += h[(size_t)n * 128 + tid];
    }
    atomicAdd(&pooled[curg * 128 + tid], acc);
}

__global__ void k_final(const float* __restrict__ pooled, const int* __restrict__ cntg,
                        const float* __restrict__ Wc, const float* __restrict__ bc,
                        float* __restrict__ out) {
    for (int idx = threadIdx.x; idx < 64 * 10; idx += 256) {
        int g = idx / 10, c = idx % 10;
        float s = 0.f;
        for (int k = 0; k < 128; ++k) s += pooled[g * 128 + k] * Wc[k * 10 + c];
        float cnt = (float)cntg[g];
        if (cnt < 1.f) cnt = 1.f;
        out[idx] = s / cnt + bc[c];
    }
}

// ---------------- launch ----------------

extern "C" void kernel_launch(void* const* d_in, const int* in_sizes, int n_in,
                              void* d_out, int out_size, void* d_ws, size_t ws_size,
                              hipStream_t stream) {
    const float* x  = (const float*)d_in[0];
    const float* W1 = (const float*)d_in[1];
    const float* b1 = (const float*)d_in[2];
    const float* W2 = (const float*)d_in[3];
    const float* b2 = (const float*)d_in[4];
    const float* Wc = (const float*)d_in[5];
    const float* bc = (const float*)d_in[6];
    const int* ei   = (const int*)d_in[7];
    const int* batch = (const int*)d_in[8];

    const int E = in_sizes[7] / 2;
    const int N = in_sizes[8];
    const int* src = ei;
    const int* dst = ei + E;

    char* p = (char*)d_ws;
    auto alloc = [&](size_t bytes) -> void* {
        void* r = (void*)p;
        p += (bytes + 255) & ~(size_t)255;
        return r;
    };
    int*   cnt      = (int*)alloc((size_t)N * 4);
    float* dinv     = (float*)alloc((size_t)N * 4);
    int*   row_ptr  = (int*)alloc((size_t)(N + 1) * 4);
    int*   bsums    = (int*)alloc(4096);
    int*   col      = (int*)alloc((size_t)E * 4);
    int*   gcnt     = (int*)alloc(NBKT * 4);
    unsigned* stage = (unsigned*)alloc((size_t)NBKT * BCAP * 4);
    unsigned short* xb    = (unsigned short*)alloc((size_t)N * 64 * 2);
    unsigned short* h1b   = (unsigned short*)alloc((size_t)N * 128 * 2);
    unsigned short* aggb1 = (unsigned short*)alloc((size_t)N * 64 * 2);
    unsigned short* aggb2 = (unsigned short*)alloc((size_t)N * 128 * 2);
    half8* w1p      = (half8*)alloc(1024 * 16);
    half8* w2p      = (half8*)alloc(2048 * 16);
    float* bufB     = (float*)alloc((size_t)N * 128 * 4);
    float* pooled   = (float*)alloc(64 * 128 * 4);
    int*   cntg     = (int*)alloc(64 * 4);

    hipMemsetAsync(gcnt, 0, NBKT * 4, stream);
    hipMemsetAsync(pooled, 0, 64 * 128 * 4, stream);

    int nb = (N + 511) / 512;

    // bucket edges, then derive degrees / CSR entirely bucket-locally (no global atomics)
    k_bucket<<<(E + TILE - 1) / TILE, 256, 0, stream>>>(src, dst, gcnt, stage, E);
    k_cnt_bucket<<<nb, 512, 0, stream>>>(stage, gcnt, cnt, N);
    k_dinv<<<(N + 255) / 256, 256, 0, stream>>>(cnt, dinv, N);
    k_scan1<<<nb, 512, 0, stream>>>(cnt, row_ptr, bsums, N);
    k_scan2<<<1, 64, 0, stream>>>(bsums, nb);
    k_scan3<<<(N + 255) / 256, 256, 0, stream>>>(row_ptr, bsums, N, E);
    k_scatter<<<nb, 512, 0, stream>>>(stage, gcnt, row_ptr, col, N);

    // weight packs + x -> bf16
    k_packW<<<4, 256, 0, stream>>>(W1, w1p, 64);
    k_packW<<<8, 256, 0, stream>>>(W2, w2p, 128);
    k_tobf16<<<(N * 64 / 8 + 255) / 256, 256, 0, stream>>>(x, xb, N * 64 / 8);

    // layer 1: aggregate x_bf16 (64 ch) -> f16, MFMA transform -> h1 bf16
    k_agg<64><<<(N + 3) / 4, 256, 0, stream>>>(xb, row_ptr, col, dinv, aggb1, N);
    k_gemm_mfma<64, true><<<(N + 63) / 64, 256, 0, stream>>>(aggb1, w1p, b1, h1b, N);

    // layer 2: aggregate h1_bf16 (128 ch) -> f16, MFMA transform -> f32
    k_agg<128><<<(N + 3) / 4, 256, 0, stream>>>(h1b, row_ptr, col, dinv, aggb2, N);
    k_gemm_mfma<128, false><<<(N + 63) / 64, 256, 0, stream>>>(aggb2, w2p, b2, bufB, N);

    // pool + classify
    k_cntg_bs<<<1, 64, 0, stream>>>(batch, cntg, N);
    k_pool<<<(N + POOL_NPB - 1) / POOL_NPB, 128, 0, stream>>>(bufB, batch, pooled, N);
    k_final<<<1, 256, 0, stream>>>(pooled, cntg, Wc, bc, (float*)d_out);
}